// Round 8
// baseline (326.109 us; speedup 1.0000x reference)
//
#include <hip/hip_runtime.h>
#include <hip/hip_bf16.h>
#include <cstdint>
#include <cmath>

typedef __bf16 bf16_t;
typedef __bf16 bf16x8 __attribute__((ext_vector_type(8)));
typedef __bf16 bf16x4 __attribute__((ext_vector_type(4)));
typedef float  f32x4  __attribute__((ext_vector_type(4)));
typedef float  f32x16 __attribute__((ext_vector_type(16)));

#define MFMA16(a, b, c) __builtin_amdgcn_mfma_f32_16x16x32_bf16(a, b, c, 0, 0, 0)
#define MFMA32(a, b, c) __builtin_amdgcn_mfma_f32_32x32x16_bf16(a, b, c, 0, 0, 0)

constexpr int   SS    = 2048;
constexpr int   DD    = 1024;
constexpr int   HH    = 16;
constexpr float SCALE = 0.125f;          // 1/sqrt(64)
constexpr float L2E   = 1.44269504088896f;

// ---------------------------------------------------------------------------
__device__ __forceinline__ bool detect_fp32(const uint16_t* w) {
    uint16_t v = w[threadIdx.x & 63];
    int e = (v >> 7) & 0xFF;
    unsigned long long m = __ballot(e >= 0x80);
    return __popcll(m) >= 4;
}

__device__ __forceinline__ float ldin(const void* p, size_t i, bool f32) {
    return f32 ? ((const float*)p)[i] : (float)((const bf16_t*)p)[i];
}

__device__ __forceinline__ void gload_lds16(const bf16_t* g, bf16_t* l) {
    __builtin_amdgcn_global_load_lds(
        (const __attribute__((address_space(1))) void*)(g),
        (__attribute__((address_space(3))) void*)(l), 16, 0, 0);
}

// Staging helpers, BK=64, XOR-swizzled (slot c holds global chunk c^(r&7)).
__device__ __forceinline__ void stage_a128(const bf16_t* A, int m0, int k0,
                                           bf16_t* As, int tid) {
#pragma unroll
    for (int i = 0; i < 4; ++i) {
        int c = tid + i * 256;
        int r = c >> 3, g = (c & 7) ^ (r & 7);
        gload_lds16(A + (size_t)(m0 + r) * DD + k0 + g * 8, As + c * 8);
    }
}
__device__ __forceinline__ void stage_b64(const bf16_t* Bt, int n0, int k0,
                                          bf16_t* Bs, int tid) {
#pragma unroll
    for (int i = 0; i < 2; ++i) {
        int c = tid + i * 256;
        int r = c >> 3, g = (c & 7) ^ (r & 7);
        gload_lds16(Bt + (size_t)(n0 + r) * DD + k0 + g * 8, Bs + c * 8);
    }
}

// ---------------------------------------------------------------------------
// Software grid barrier, single-use per launch. w[0]=arrive cnt, w[1]=release
// flag; both zeroed every iteration by the hipMemsetAsync node captured into
// the graph (ws is re-poisoned between iterations, so in-kernel reset cannot
// work). Device-scope atomics reach the coherent point across XCDs (G12/m20);
// __threadfence gives agent-scope release/acquire around the rendezvous.
__device__ __forceinline__ void grid_bar(unsigned* w) {
    __syncthreads();
    if (threadIdx.x == 0) {
        __threadfence();                               // release my stores
        if (atomicAdd(w, 1u) == 511u) {                // 512 blocks
            atomicExch(w + 1, 1u);
        } else {
            while (atomicOr(w + 1, 0u) == 0u) __builtin_amdgcn_s_sleep(8);
        }
        __threadfence();                               // acquire their stores
    }
    __syncthreads();
}

// ---------------------------------------------------------------------------
// Round-16: single ORDINARY kernel + sw grid barriers (coop launch is dead
// under graph capture: rounds 5/6 byte-identical absmax => never executed).
// 512 blocks x 256 thr, __launch_bounds__(256,2): VGPR<=256 -> 8 waves/CU ->
// exactly 2 blocks/CU co-resident on the idle GPU; grid == capacity, so all
// blocks are dispatched before any completes. Phases are the harness-verified
// round-7 kernels, load-balanced: B pairs job b with 1023-b (heavy+light),
// C does b and b+512. Theory under test: ~15 us/dispatch fixed overhead
// (launch+ramp+drain) x 4 is the ~65 us residual no inner-loop change moves.
__global__ __launch_bounds__(256, 2) void mega_kernel(
    const void* __restrict__ hidden, const void* __restrict__ Wq,
    const void* __restrict__ Wk, const void* __restrict__ Wv,
    const void* __restrict__ Wo,
    bf16_t* __restrict__ roped, bf16_t* __restrict__ hiddenb,
    bf16_t* __restrict__ WqT, bf16_t* __restrict__ WkT,
    bf16_t* __restrict__ WvT, bf16_t* __restrict__ WoT,
    bf16_t* __restrict__ Qb, bf16_t* __restrict__ Kb,
    bf16_t* __restrict__ Vt, bf16_t* __restrict__ attnb,
    void* __restrict__ out, unsigned* __restrict__ bars) {
    __shared__ __align__(16) char smem[32768];
    const int tid  = threadIdx.x, lane = tid & 63;
    const bool f32 = detect_fp32((const uint16_t*)Wq);

    // ---------------- Phase A: RoPE + weight transpose (10 jobs/block) -----
    {
        bf16_t (*tile)[33] = reinterpret_cast<bf16_t(*)[33]>(smem);
        for (int vb = blockIdx.x; vb < 5120; vb += 512) {
            if (vb < 1024) {
                int gid = vb * 256 + tid;
                int ic = (gid & 3) * 8;
                int h  = (gid >> 2) & 15;
                int s  = (gid >> 6) & 2047;
                int b  = gid >> 17;
                size_t base = ((size_t)(b * SS + s)) * DD + h * 64 + ic;
                float x[8], y[8];
                if (f32) {
                    const float* hp = (const float*)hidden;
                    f32x4 x0 = *(const f32x4*)(hp + base);
                    f32x4 x1 = *(const f32x4*)(hp + base + 4);
                    f32x4 y0 = *(const f32x4*)(hp + base + 32);
                    f32x4 y1 = *(const f32x4*)(hp + base + 36);
#pragma unroll
                    for (int j = 0; j < 4; ++j) {
                        x[j] = x0[j]; x[4 + j] = x1[j];
                        y[j] = y0[j]; y[4 + j] = y1[j];
                    }
                } else {
                    const bf16_t* hp = (const bf16_t*)hidden;
                    bf16x8 xv = *(const bf16x8*)(hp + base);
                    bf16x8 yv = *(const bf16x8*)(hp + base + 32);
#pragma unroll
                    for (int j = 0; j < 8; ++j) { x[j] = (float)xv[j]; y[j] = (float)yv[j]; }
                }
                bf16x8 ro, rh;
#pragma unroll
                for (int j = 0; j < 8; ++j) {
                    int i = ic + j;
                    float invf = exp2f(-(float)i * (13.287712379549449f / 32.0f));
                    float sn, cs;
                    __sincosf((float)s * invf, &sn, &cs);
                    ro[j] = (bf16_t)(x[j] * cs - y[j] * sn);
                    rh[j] = (bf16_t)(y[j] * cs + x[j] * sn);
                }
                *(bf16x8*)(roped + base)      = ro;
                *(bf16x8*)(roped + base + 32) = rh;
                if (f32) {
                    bf16x8 hb0, hb1;
#pragma unroll
                    for (int j = 0; j < 8; ++j) { hb0[j] = (bf16_t)x[j]; hb1[j] = (bf16_t)y[j]; }
                    *(bf16x8*)(hiddenb + base)      = hb0;
                    *(bf16x8*)(hiddenb + base + 32) = hb1;
                }
            } else {
                int w = vb - 1024;
                int z = w >> 10;
                int yy = (w >> 5) & 31, xx = w & 31;
                const void* src = (z == 0) ? Wq : (z == 1) ? Wk : (z == 2) ? Wv : Wo;
                bf16_t*     dst = (z == 0) ? WqT : (z == 1) ? WkT : (z == 2) ? WvT : WoT;
                int tx = tid & 31, ty = tid >> 5;
                int x0 = xx * 32, y0 = yy * 32;
#pragma unroll
                for (int j = 0; j < 4; ++j)
                    tile[ty + j * 8][tx] =
                        (bf16_t)ldin(src, (size_t)(y0 + ty + j * 8) * DD + x0 + tx, f32);
                __syncthreads();
#pragma unroll
                for (int j = 0; j < 4; ++j)
                    dst[(size_t)(x0 + ty + j * 8) * DD + y0 + tx] = tile[tx][ty + j * 8];
                __syncthreads();   // tile reused next iteration
            }
        }
    }
    grid_bar(bars + 0);

    // ---------------- Phase B: fused QKV, 1024 jobs, b paired with 1023-b --
    {
        bf16_t* As = (bf16_t*)smem;                 // 16 KB
        bf16_t* B1 = (bf16_t*)(smem + 16384);       //  8 KB
        bf16_t* B2 = (bf16_t*)(smem + 24576);       //  8 KB
        const int l32 = lane & 31, kh = lane >> 5;
        const int wave = tid >> 6, wm = (wave >> 1) * 64, wn = (wave & 1) * 32;
        const int sw = l32 & 7;
#pragma unroll 1
        for (int rpt = 0; rpt < 2; ++rpt) {
            const int lin = (rpt == 0) ? (int)blockIdx.x : 1023 - (int)blockIdx.x;
            const int z   = lin & 1;                 // parity flips with rpt
            const int p   = lin >> 1;
            const int xcd = p & 7, rem = p >> 3;
            const int mb  = (xcd >> 1) * 8 + (rem >> 3);
            const int nb  = (xcd & 1) * 8 + (rem & 7);
            const int m0  = mb * 128, n0 = nb * 64;

            if (z == 0) {
                f32x16 accq[2], acck[2];
                accq[0] = (f32x16)0.0f; accq[1] = (f32x16)0.0f;
                acck[0] = (f32x16)0.0f; acck[1] = (f32x16)0.0f;
                for (int k0 = 0; k0 < DD; k0 += 64) {
                    stage_a128(roped, m0, k0, As, tid);
                    stage_b64(WqT, n0, k0, B1, tid);
                    stage_b64(WkT, n0, k0, B2, tid);
                    __syncthreads();
#pragma unroll
                    for (int kk = 0; kk < 4; ++kk) {
                        const int c8 = (kk * 2 + kh) ^ sw;
                        bf16x8 a0 = *(const bf16x8*)(As + (wm      + l32) * 64 + c8 * 8);
                        bf16x8 a1 = *(const bf16x8*)(As + (wm + 32 + l32) * 64 + c8 * 8);
                        bf16x8 bq = *(const bf16x8*)(B1 + (wn + l32) * 64 + c8 * 8);
                        bf16x8 bk = *(const bf16x8*)(B2 + (wn + l32) * 64 + c8 * 8);
                        accq[0] = MFMA32(a0, bq, accq[0]);
                        accq[1] = MFMA32(a1, bq, accq[1]);
                        acck[0] = MFMA32(a0, bk, acck[0]);
                        acck[1] = MFMA32(a1, bk, acck[1]);
                    }
                    __syncthreads();
                }
                const int d = wn + l32;
#pragma unroll
                for (int i = 0; i < 2; ++i) {
#pragma unroll
                    for (int q4 = 0; q4 < 4; ++q4) {
                        int row = m0 + wm + i * 32 + q4 * 8 + kh * 4;
                        int bb = row >> 11, sl = row & 2047;
                        size_t base = (((size_t)bb * HH + nb) * SS + sl) * 64 + d;
#pragma unroll
                        for (int r = 0; r < 4; ++r) {
                            Qb[base + 64 * r] = (bf16_t)accq[i][q4 * 4 + r];
                            Kb[base + 64 * r] = (bf16_t)acck[i][q4 * 4 + r];
                        }
                    }
                }
            } else {
                const bf16_t* A = f32 ? hiddenb : (const bf16_t*)hidden;
                f32x16 accv[2];
                accv[0] = (f32x16)0.0f; accv[1] = (f32x16)0.0f;
                for (int k0 = 0; k0 < DD; k0 += 64) {
                    stage_a128(A, m0, k0, As, tid);
                    stage_b64(WvT, n0, k0, B1, tid);
                    __syncthreads();
#pragma unroll
                    for (int kk = 0; kk < 4; ++kk) {
                        const int c8 = (kk * 2 + kh) ^ sw;
                        bf16x8 a0 = *(const bf16x8*)(As + (wm      + l32) * 64 + c8 * 8);
                        bf16x8 a1 = *(const bf16x8*)(As + (wm + 32 + l32) * 64 + c8 * 8);
                        bf16x8 bv = *(const bf16x8*)(B1 + (wn + l32) * 64 + c8 * 8);
                        accv[0] = MFMA32(a0, bv, accv[0]);
                        accv[1] = MFMA32(a1, bv, accv[1]);
                    }
                    __syncthreads();
                }
                const int d = wn + l32;                 // V -> [b,h,d,s]
#pragma unroll
                for (int i = 0; i < 2; ++i) {
#pragma unroll
                    for (int q4 = 0; q4 < 4; ++q4) {
                        int row = m0 + wm + i * 32 + q4 * 8 + kh * 4;
                        int bb = row >> 11, sl = row & 2047;
                        bf16x4 v;
                        v[0] = (bf16_t)accv[i][q4 * 4 + 0];
                        v[1] = (bf16_t)accv[i][q4 * 4 + 1];
                        v[2] = (bf16_t)accv[i][q4 * 4 + 2];
                        v[3] = (bf16_t)accv[i][q4 * 4 + 3];
                        *(bf16x4*)(Vt + (((size_t)bb * HH + nb) * 64 + d) * SS + sl) = v;
                    }
                }
            }
            __syncthreads();   // all waves done with As/B1/B2 before next rpt
        }
    }
    grid_bar(bars + 2);

    // ---------------- Phase C: banded flash attention, jobs b and b+512 ----
    {
        bf16_t* KsB = (bf16_t*)smem;            // [2][32*64]
        bf16_t* VsB = (bf16_t*)(smem + 8192);   // [2][64*32]
        bf16_t* PlB = (bf16_t*)(smem + 16384);  // [4][16*40]
        const int wave = tid >> 6;
        const int quad = lane >> 4, l16 = lane & 15;
        const int sw7 = l16 & 7, sw3 = l16 & 3;
        bf16_t* P = PlB + wave * 640;

#pragma unroll 1
        for (int rpt = 0; rpt < 2; ++rpt) {
            const int vt = (int)blockIdx.x + rpt * 512;
            int lin = (vt >> 3) + 128 * (vt & 7);   // XCD swizzle
            const int qb0 = (lin & 31) * 64;
            const int h   = (lin >> 5) & 15;
            const int b   = lin >> 9;
            const int qw  = qb0 + wave * 16;

            const size_t bh = (size_t)b * HH + h;
            const bf16_t* Qp = Qb + bh * SS * 64;
            const bf16_t* Kp = Kb + bh * SS * 64;
            const bf16_t* Vp = Vt + bh * 64 * SS;

            bf16x8 q0 = *(const bf16x8*)(Qp + (size_t)(qw + l16) * 64 + quad * 8);
            bf16x8 q1 = *(const bf16x8*)(Qp + (size_t)(qw + l16) * 64 + 32 + quad * 8);

            f32x4 Oacc[4];
#pragma unroll
            for (int t = 0; t < 4; ++t) Oacc[t] = (f32x4)0.0f;
            float lsum[4] = {0.f, 0.f, 0.f, 0.f};

            int lo = qb0 - 127; if (lo < 0) lo = 0; lo &= ~31;
            int hi = qb0 + 63 + 127; if (hi > SS - 1) hi = SS - 1;

            const int krow = tid >> 3, kcol = ((tid & 7) ^ (krow & 7)) * 8;
            const int vrow = tid >> 2, vcol = ((tid & 3) ^ (vrow & 3)) * 8;

            int parity = 0;
            for (int kt = lo; kt <= hi; kt += 32, parity ^= 1) {
                gload_lds16(Kp + (size_t)(kt + krow) * 64 + kcol,
                            KsB + parity * 2048 + tid * 8);
                gload_lds16(Vp + (size_t)vrow * SS + kt + vcol,
                            VsB + parity * 2048 + tid * 8);
                __syncthreads();

                const bf16_t* Kl = KsB + parity * 2048;
                const bf16_t* Vl = VsB + parity * 2048;
                bf16x8 k00 = *(const bf16x8*)(Kl + l16 * 64 + (quad ^ sw7) * 8);
                bf16x8 k01 = *(const bf16x8*)(Kl + l16 * 64 + ((quad + 4) ^ sw7) * 8);
                bf16x8 k10 = *(const bf16x8*)(Kl + (16 + l16) * 64 + (quad ^ sw7) * 8);
                bf16x8 k11 = *(const bf16x8*)(Kl + (16 + l16) * 64 + ((quad + 4) ^ sw7) * 8);
                bf16x8 vf[4];
#pragma unroll
                for (int t = 0; t < 4; ++t)
                    vf[t] = *(const bf16x8*)(Vl + (t * 16 + l16) * 32 + (quad ^ sw3) * 8);

                f32x4 s0 = MFMA16(q0, k00, (f32x4)0.0f);  s0 = MFMA16(q1, k01, s0);
                f32x4 s1 = MFMA16(q0, k10, (f32x4)0.0f);  s1 = MFMA16(q1, k11, s1);

                const int kr0 = kt + l16, kr1 = kt + 16 + l16;
#pragma unroll
                for (int r = 0; r < 4; ++r) {
                    int qa = qw + quad * 4 + r;
                    int d0 = qa - kr0; if (d0 < 0) d0 = -d0;
                    int d1 = qa - kr1; if (d1 < 0) d1 = -d1;
                    float p0 = (d0 < 128) ? exp2f(s0[r] * (SCALE * L2E)) : 0.0f;
                    float p1 = (d1 < 128) ? exp2f(s1[r] * (SCALE * L2E)) : 0.0f;
                    lsum[r] += p0 + p1;
                    P[(quad * 4 + r) * 40 + l16]      = (bf16_t)p0;
                    P[(quad * 4 + r) * 40 + 16 + l16] = (bf16_t)p1;
                }
                __asm__ volatile("s_waitcnt lgkmcnt(0)" ::: "memory");
                __builtin_amdgcn_sched_barrier(0);
                bf16x8 pf = *(const bf16x8*)(P + l16 * 40 + quad * 8);
#pragma unroll
                for (int t = 0; t < 4; ++t)
                    Oacc[t] = MFMA16(pf, vf[t], Oacc[t]);
            }
            __syncthreads();   // parity resets next rpt — protect Ks/Vs reuse

#pragma unroll
            for (int r = 0; r < 4; ++r) {
                float l = lsum[r];
                l += __shfl_xor(l, 1, 64);
                l += __shfl_xor(l, 2, 64);
                l += __shfl_xor(l, 4, 64);
                l += __shfl_xor(l, 8, 64);
                float inv = 1.0f / l;
                int sa = qw + quad * 4 + r;
                size_t base = (((size_t)b * SS + sa) * HH + h) * 64 + l16;
                attnb[base]      = (bf16_t)(Oacc[0][r] * inv);
                attnb[base + 16] = (bf16_t)(Oacc[1][r] * inv);
                attnb[base + 32] = (bf16_t)(Oacc[2][r] * inv);
                attnb[base + 48] = (bf16_t)(Oacc[3][r] * inv);
            }
        }
    }
    grid_bar(bars + 4);

    // ---------------- Phase D: output projection, 512 jobs, 1/block --------
    {
        bf16_t* As = (bf16_t*)smem;
        bf16_t* B1 = (bf16_t*)(smem + 16384);
        const int l32 = lane & 31, kh = lane >> 5;
        const int wave = tid >> 6, wm = (wave >> 1) * 64, wn = (wave & 1) * 32;
        const int sw = l32 & 7;

        const int lin = blockIdx.x;
        const int xcd = lin & 7, s = lin >> 3;
        const int mb = (xcd >> 1) * 8 + (s >> 3);
        const int nb = (xcd & 1) * 8 + (s & 7);
        const int m0 = mb * 128, n0 = nb * 64;

        f32x16 acc[2];
        acc[0] = (f32x16)0.0f; acc[1] = (f32x16)0.0f;

        for (int k0 = 0; k0 < DD; k0 += 64) {
            stage_a128(attnb, m0, k0, As, tid);
            stage_b64(WoT, n0, k0, B1, tid);
            __syncthreads();
#pragma unroll
            for (int kk = 0; kk < 4; ++kk) {
                const int c8 = (kk * 2 + kh) ^ sw;
                bf16x8 a0 = *(const bf16x8*)(As + (wm      + l32) * 64 + c8 * 8);
                bf16x8 a1 = *(const bf16x8*)(As + (wm + 32 + l32) * 64 + c8 * 8);
                bf16x8 b0 = *(const bf16x8*)(B1 + (wn + l32) * 64 + c8 * 8);
                acc[0] = MFMA32(a0, b0, acc[0]);
                acc[1] = MFMA32(a1, b0, acc[1]);
            }
            __syncthreads();
        }

        const int n = n0 + wn + l32;
#pragma unroll
        for (int i = 0; i < 2; ++i) {
#pragma unroll
            for (int q4 = 0; q4 < 4; ++q4) {
                int row = m0 + wm + i * 32 + q4 * 8 + kh * 4;
#pragma unroll
                for (int r = 0; r < 4; ++r) {
                    size_t idx = (size_t)(row + r) * DD + n;
                    if (f32) ((float*)out)[idx] = acc[i][q4 * 4 + r];
                    else     ((bf16_t*)out)[idx] = (bf16_t)acc[i][q4 * 4 + r];
                }
            }
        }
    }
}

// ---------------------------------------------------------------------------
extern "C" void kernel_launch(void* const* d_in, const int* in_sizes, int n_in,
                              void* d_out, int out_size, void* d_ws, size_t ws_size,
                              hipStream_t stream) {
    const void* hidden = d_in[0];
    const void* Wq = d_in[1];
    const void* Wk = d_in[2];
    const void* Wv = d_in[3];
    const void* Wo = d_in[4];
    char* ws = (char*)d_ws;

    bf16_t* roped   = (bf16_t*)(ws);                  // 8 MiB (b,s,d)
    bf16_t* hiddenb = (bf16_t*)(ws + ( 8u << 20));    // 8 MiB (fp32 path only)
    bf16_t* WqT     = (bf16_t*)(ws + (16u << 20));    // 2 MiB each, [n][k]
    bf16_t* WkT     = (bf16_t*)(ws + (18u << 20));
    bf16_t* WvT     = (bf16_t*)(ws + (20u << 20));
    bf16_t* WoT     = (bf16_t*)(ws + (22u << 20));
    bf16_t* Qb      = (bf16_t*)(ws + (24u << 20));    // 8 MiB (b,h,s,d)
    bf16_t* Kb      = (bf16_t*)(ws + (32u << 20));    // 8 MiB (b,h,s,d)
    bf16_t* Vt      = (bf16_t*)(ws + (40u << 20));    // 8 MiB (b,h,d,s)
    bf16_t* attnb   = (bf16_t*)(ws + (48u << 20));    // 8 MiB — own region
    unsigned* bars  = (unsigned*)(ws + (60u << 20));  // 3 barriers x 2 words

    // memset node is captured into the graph -> re-zeroes barriers every
    // replay (ws is re-poisoned between iterations; memsetAsync is not on
    // the forbidden list, G9).
    hipMemsetAsync(bars, 0, 256, stream);

    hipLaunchKernelGGL(mega_kernel, dim3(512), dim3(256), 0, stream,
                       hidden, Wq, Wk, Wv, Wo, roped, hiddenb,
                       WqT, WkT, WvT, WoT, Qb, Kb, Vt, attnb, d_out, bars);
}